// Round 2
// baseline (126.227 us; speedup 1.0000x reference)
//
#include <hip/hip_runtime.h>

#define EPS 1e-5f

// 4 neighbors per thread (K=16 -> 4 threads per point).
// Loads: 3x float4 per thread (48 B contiguous, fully vectorized).
// Stores: 8x float4 per thread (128 B contiguous).
// BN folded: y[o] = relu(fma(dot(W[o], x), scale[o], shift[o])), constants
// computed once per thread, amortized over 4 neighbors. W via uniform s_loads.
__global__ __launch_bounds__(256) void lse_kernel(
    const float* __restrict__ coords,   // (B,N,3)
    const float* __restrict__ nbr,      // (B,N,K,3)
    const float* __restrict__ W1,       // (4,4) row-major (o,c)
    const float* __restrict__ g1, const float* __restrict__ b1,
    const float* __restrict__ m1, const float* __restrict__ v1,
    const float* __restrict__ W2,       // (8,4) row-major (o,c)
    const float* __restrict__ g2, const float* __restrict__ b2,
    const float* __restrict__ m2, const float* __restrict__ v2,
    float* __restrict__ out,            // (B,N,K,8)
    int nthreads)                       // B*N*K/4
{
    int tid = blockIdx.x * blockDim.x + threadIdx.x;
    if (tid >= nthreads) return;

    // ---- BN affine params (uniform; once per thread, amortized over 4 nbrs) ----
    float sc1[4], sh1[4];
#pragma unroll
    for (int o = 0; o < 4; ++o) {
        float s = g1[o] * rsqrtf(v1[o] + EPS);
        sc1[o] = s;
        sh1[o] = b1[o] - m1[o] * s;
    }
    float sc2[8], sh2[8];
#pragma unroll
    for (int o = 0; o < 8; ++o) {
        float s = g2[o] * rsqrtf(v2[o] + EPS);
        sc2[o] = s;
        sh2[o] = b2[o] - m2[o] * s;
    }

    // ---- center coords (shared by this thread's 4 neighbors) ----
    int bn = tid >> 2;  // 4 neighbors per thread, K=16
    float cx = coords[bn * 3 + 0];
    float cy = coords[bn * 3 + 1];
    float cz = coords[bn * 3 + 2];

    // ---- 4 neighbors: 48 B contiguous = 3x float4 ----
    const float4* np4 = (const float4*)(nbr + (size_t)tid * 12);
    float4 p0 = np4[0];
    float4 p1 = np4[1];
    float4 p2 = np4[2];
    float nx[4] = {p0.x, p0.w, p1.z, p2.y};
    float ny[4] = {p0.y, p1.x, p1.w, p2.z};
    float nz[4] = {p0.z, p1.y, p2.x, p2.w};

    float4* op = (float4*)(out + (size_t)tid * 32);

#pragma unroll
    for (int k = 0; k < 4; ++k) {
        float rx = nx[k] - cx, ry = ny[k] - cy, rz = nz[k] - cz;
        float dist = sqrtf(rx * rx + ry * ry + rz * rz);
        float enc[4] = {rx, ry, rz, dist};

        // layer 1: 4 -> 4, BN + ReLU
        float h[4];
#pragma unroll
        for (int o = 0; o < 4; ++o) {
            float a = 0.f;
#pragma unroll
            for (int c = 0; c < 4; ++c) a = fmaf(W1[o * 4 + c], enc[c], a);
            h[o] = fmaxf(fmaf(a, sc1[o], sh1[o]), 0.f);
        }

        // layer 2: 4 -> 8, BN + ReLU
        float r[8];
#pragma unroll
        for (int o = 0; o < 8; ++o) {
            float a = 0.f;
#pragma unroll
            for (int c = 0; c < 4; ++c) a = fmaf(W2[o * 4 + c], h[c], a);
            r[o] = fmaxf(fmaf(a, sc2[o], sh2[o]), 0.f);
        }

        op[2 * k + 0] = make_float4(r[0], r[1], r[2], r[3]);
        op[2 * k + 1] = make_float4(r[4], r[5], r[6], r[7]);
    }
}

extern "C" void kernel_launch(void* const* d_in, const int* in_sizes, int n_in,
                              void* d_out, int out_size, void* d_ws, size_t ws_size,
                              hipStream_t stream) {
    const float* coords = (const float*)d_in[0];
    const float* nbr    = (const float*)d_in[1];
    const float* W1     = (const float*)d_in[2];
    const float* g1     = (const float*)d_in[3];
    const float* b1     = (const float*)d_in[4];
    const float* m1     = (const float*)d_in[5];
    const float* v1     = (const float*)d_in[6];
    const float* W2     = (const float*)d_in[7];
    const float* g2     = (const float*)d_in[8];
    const float* b2     = (const float*)d_in[9];
    const float* m2     = (const float*)d_in[10];
    const float* v2     = (const float*)d_in[11];
    float* out = (float*)d_out;

    int total    = in_sizes[1] / 3;  // B*N*K neighbors
    int nthreads = total / 4;        // 4 neighbors per thread (K=16 divisible)
    int block = 256;
    int grid = (nthreads + block - 1) / block;
    lse_kernel<<<grid, block, 0, stream>>>(coords, nbr, W1, g1, b1, m1, v1,
                                           W2, g2, b2, m2, v2, out, nthreads);
}

// Round 3
// 115.737 us; speedup vs baseline: 1.0906x; 1.0906x over previous
//
#include <hip/hip_runtime.h>

#define EPS 1e-5f

// Pre-kernel: fold BN into weights once (runs every launch; deterministic).
// cst layout (floats): [0:16) W1f row-major (o,c), [16:20) sh1,
//                      [20:52) W2f row-major (o,c), [52:60) sh2.
__global__ void fold_params(
    const float* __restrict__ W1, const float* __restrict__ g1,
    const float* __restrict__ b1, const float* __restrict__ m1,
    const float* __restrict__ v1,
    const float* __restrict__ W2, const float* __restrict__ g2,
    const float* __restrict__ b2, const float* __restrict__ m2,
    const float* __restrict__ v2,
    float* __restrict__ cst)
{
    if (threadIdx.x == 0 && blockIdx.x == 0) {
        for (int o = 0; o < 4; ++o) {
            float s = g1[o] * rsqrtf(v1[o] + EPS);
            for (int c = 0; c < 4; ++c) cst[o * 4 + c] = W1[o * 4 + c] * s;
            cst[16 + o] = b1[o] - m1[o] * s;
        }
        for (int o = 0; o < 8; ++o) {
            float s = g2[o] * rsqrtf(v2[o] + EPS);
            for (int c = 0; c < 4; ++c) cst[20 + o * 4 + c] = W2[o * 4 + c] * s;
            cst[52 + o] = b2[o] - m2[o] * s;
        }
    }
}

// One thread per (b,n,k) neighbor — R1's best-measured access pattern:
// loads 3x b32 (12-B lane stride), stores 2x b128 (32-B lane stride, dense region).
// All BN/weight constants pre-folded -> uniform s_loads; per-thread VALU ~67 ops.
__global__ __launch_bounds__(256) void lse_kernel(
    const float* __restrict__ coords,   // (B,N,3)
    const float* __restrict__ nbr,      // (B,N,K,3)
    const float* __restrict__ cst,      // 60 folded constants
    float* __restrict__ out,            // (B,N,K,8)
    int total)                          // B*N*K
{
    int tid = blockIdx.x * blockDim.x + threadIdx.x;
    if (tid >= total) return;

    // encoding
    int bn = tid >> 4;  // K = 16
    float cx = coords[bn * 3 + 0];
    float cy = coords[bn * 3 + 1];
    float cz = coords[bn * 3 + 2];
    float rx = nbr[(size_t)tid * 3 + 0] - cx;
    float ry = nbr[(size_t)tid * 3 + 1] - cy;
    float rz = nbr[(size_t)tid * 3 + 2] - cz;
    float dist = sqrtf(rx * rx + ry * ry + rz * rz);
    float enc[4] = {rx, ry, rz, dist};

    // layer 1: 4 -> 4 (BN pre-folded), ReLU
    float h[4];
#pragma unroll
    for (int o = 0; o < 4; ++o) {
        float a = cst[16 + o];
#pragma unroll
        for (int c = 0; c < 4; ++c) a = fmaf(cst[o * 4 + c], enc[c], a);
        h[o] = fmaxf(a, 0.f);
    }

    // layer 2: 4 -> 8 (BN pre-folded), ReLU
    float r[8];
#pragma unroll
    for (int o = 0; o < 8; ++o) {
        float a = cst[52 + o];
#pragma unroll
        for (int c = 0; c < 4; ++c) a = fmaf(cst[20 + o * 4 + c], h[c], a);
        r[o] = fmaxf(a, 0.f);
    }

    // store 32 B as two float4
    float4* op = (float4*)(out + (size_t)tid * 8);
    op[0] = make_float4(r[0], r[1], r[2], r[3]);
    op[1] = make_float4(r[4], r[5], r[6], r[7]);
}

extern "C" void kernel_launch(void* const* d_in, const int* in_sizes, int n_in,
                              void* d_out, int out_size, void* d_ws, size_t ws_size,
                              hipStream_t stream) {
    const float* coords = (const float*)d_in[0];
    const float* nbr    = (const float*)d_in[1];
    float* cst = (float*)d_ws;   // 60 floats of folded constants
    float* out = (float*)d_out;

    fold_params<<<1, 64, 0, stream>>>((const float*)d_in[2], (const float*)d_in[3],
                                      (const float*)d_in[4], (const float*)d_in[5],
                                      (const float*)d_in[6], (const float*)d_in[7],
                                      (const float*)d_in[8], (const float*)d_in[9],
                                      (const float*)d_in[10], (const float*)d_in[11],
                                      cst);

    int total = in_sizes[1] / 3;  // B*N*K
    int block = 256;
    int grid = (total + block - 1) / block;
    lse_kernel<<<grid, block, 0, stream>>>(coords, nbr, cst, out, total);
}